// Round 1
// baseline (54202.527 us; speedup 1.0000x reference)
//
#include <hip/hip_runtime.h>
#include <hip/hip_cooperative_groups.h>

namespace cg = cooperative_groups;

// Problem dims (fixed by reference)
constexpr int kB  = 512;   // batch
constexpr int kT  = 512;   // seq len
constexpr int kI  = 128;   // input dim
constexpr int kH  = 512;   // hidden
constexpr int kNG = 2048;  // 4*H, gate order [g,i,f,o]
constexpr int kO  = 128;   // output dim

constexpr int HS_LD = 68;  // padded LDS leading dim for h/x/z tiles (16B-aligned rows, no 4-way conflicts)

__device__ __forceinline__ float fsig(float v)  { return 1.0f / (1.0f + __expf(-v)); }
__device__ __forceinline__ float ftanh(float v) { return 1.0f - 2.0f / (1.0f + __expf(2.0f * v)); }

// Grid: 256 WGs x 256 threads (1 WG/CU, cooperative).
// WG wg: bg = wg>>5 (8 batch groups of 64 rows), ng = wg&31 (32 h-slices of 16).
// Tile cols cc in [0,64): global gate col n(cc) = (cc>>4)*512 + ng*16 + (cc&15).
__global__ __launch_bounds__(256) void lstm_fused(
    const float* __restrict__ x,  const float* __restrict__ Wx,
    const float* __restrict__ Wh, const float* __restrict__ bias,
    const float* __restrict__ Wp, const float* __restrict__ bp,
    float* __restrict__ out, float* __restrict__ ws)
{
  cg::grid_group grid = cg::this_grid();

  __shared__ float smem[64 * HS_LD + 64 * 64];
  float* hs  = smem;               // [64][HS_LD]  src (h or x) tile; reused as z tile
  float* wss = smem + 64 * HS_LD;  // [64][64]     weight tile (gate-gathered cols)

  float* h0 = ws;             // [512][512]
  float* h1 = ws + kB * kH;   // [512][512]

  const int tid = threadIdx.x;
  const int wg  = blockIdx.x;
  const int bg  = wg >> 5;
  const int ng  = wg & 31;
  const int b0  = bg * 64;

  const int ty = tid >> 4;      // 0..15
  const int tx = tid & 15;      // 0..15
  const int r0 = ty * 4;        // 4 rows per thread
  const int gate = tx >> 2;     // this thread's gate strip in GEMM cols
  const int hq   = tx & 3;
  const int ncol0 = gate * 512 + ng * 16 + hq * 4;  // global col of acc[.]{x}

  const int lr = tid >> 4;      // staging: row group
  const int lc = tid & 15;      // staging: col quad

  // zero h0 (ws is poisoned)
  for (int i = wg * 256 + tid; i < kB * kH; i += 256 * 256) h0[i] = 0.0f;

  const float4 bv = *reinterpret_cast<const float4*>(&bias[ncol0]);

  float creg[4] = {0.f, 0.f, 0.f, 0.f};

  grid.sync();

  for (int t = 0; t < kT; ++t) {
    const float* hc = (t & 1) ? h1 : h0;
    float*       hn = (t & 1) ? h0 : h1;

    float4 acc0 = bv, acc1 = bv, acc2 = bv, acc3 = bv;

    // 8 chunks of h@Wh (K=512) + 2 chunks of x_t@Wx (K=128)
    for (int chunk = 0; chunk < 10; ++chunk) {
      const float* src; long srcStride; const float* W; int kb;
      if (chunk < 8) {
        src = hc + (long)b0 * kH; srcStride = kH; W = Wh; kb = chunk * 64;
      } else {
        src = x + (long)b0 * (kT * kI) + (long)t * kI; srcStride = (long)kT * kI; W = Wx; kb = (chunk - 8) * 64;
      }

      // stage src tile: [64 rows][kb..kb+63]
      #pragma unroll
      for (int rr = 0; rr < 4; ++rr) {
        int row = lr + rr * 16;
        float4 v = *reinterpret_cast<const float4*>(&src[(long)row * srcStride + kb + lc * 4]);
        *reinterpret_cast<float4*>(&hs[row * HS_LD + lc * 4]) = v;
      }
      // stage W tile: [kb..kb+63][n(cc)] gathered into [64][64]
      {
        const int ncolW = (lc >> 2) * 512 + ng * 16 + (lc & 3) * 4;
        #pragma unroll
        for (int rr = 0; rr < 4; ++rr) {
          int k = lr + rr * 16;
          float4 v = *reinterpret_cast<const float4*>(&W[(long)(kb + k) * kNG + ncolW]);
          *reinterpret_cast<float4*>(&wss[k * 64 + lc * 4]) = v;
        }
      }
      __syncthreads();

      #pragma unroll 16
      for (int k = 0; k < 64; ++k) {
        float4 wv = *reinterpret_cast<const float4*>(&wss[k * 64 + tx * 4]);
        float a0 = hs[(r0 + 0) * HS_LD + k];
        float a1 = hs[(r0 + 1) * HS_LD + k];
        float a2 = hs[(r0 + 2) * HS_LD + k];
        float a3 = hs[(r0 + 3) * HS_LD + k];
        acc0.x += a0 * wv.x; acc0.y += a0 * wv.y; acc0.z += a0 * wv.z; acc0.w += a0 * wv.w;
        acc1.x += a1 * wv.x; acc1.y += a1 * wv.y; acc1.z += a1 * wv.z; acc1.w += a1 * wv.w;
        acc2.x += a2 * wv.x; acc2.y += a2 * wv.y; acc2.z += a2 * wv.z; acc2.w += a2 * wv.w;
        acc3.x += a3 * wv.x; acc3.y += a3 * wv.y; acc3.z += a3 * wv.z; acc3.w += a3 * wv.w;
      }
      __syncthreads();
    }

    // write z tile to LDS (reuse hs region), then gate update
    float* zs = hs;
    *reinterpret_cast<float4*>(&zs[(r0 + 0) * HS_LD + tx * 4]) = acc0;
    *reinterpret_cast<float4*>(&zs[(r0 + 1) * HS_LD + tx * 4]) = acc1;
    *reinterpret_cast<float4*>(&zs[(r0 + 2) * HS_LD + tx * 4]) = acc2;
    *reinterpret_cast<float4*>(&zs[(r0 + 3) * HS_LD + tx * 4]) = acc3;
    __syncthreads();

    // update: this thread owns rows r0..r0+3, h-col (ng*16 + tx); c stays in regs
    #pragma unroll
    for (int i = 0; i < 4; ++i) {
      float zg = zs[(r0 + i) * HS_LD +  0 + tx];
      float zi = zs[(r0 + i) * HS_LD + 16 + tx];
      float zf = zs[(r0 + i) * HS_LD + 32 + tx];
      float zo = zs[(r0 + i) * HS_LD + 48 + tx];
      float g  = ftanh(zg);
      float ii = fsig(zi);
      float ff = fsig(zf);
      float oo = fsig(zo);
      float cn = g * ii + creg[i] * ff;
      creg[i] = cn;
      float hv = ftanh(cn) * oo;
      hn[(long)(b0 + r0 + i) * kH + ng * 16 + tx] = hv;
    }
    __threadfence();
    grid.sync();
  }

  // ---- projection + softmax: p = h_final @ Wp + bp; softmax over O=128 per row
  const float* hf = h0;  // T even -> final h in h0
  // each WG handles rows wg*2, wg*2+1
  float* hrow = smem;            // [2][512]
  float* red  = smem + 2 * kH;   // [256]
  for (int i = tid; i < 2 * kH; i += 256) {
    int r = i >> 9, k = i & 511;
    hrow[i] = hf[(long)(wg * 2 + r) * kH + k];
  }
  __syncthreads();

  const int orow = tid >> 7;   // 0..1
  const int oc   = tid & 127;  // 0..127
  float p = bp[oc];
  #pragma unroll 8
  for (int k = 0; k < kH; ++k)
    p += hrow[orow * kH + k] * Wp[(long)k * kO + oc];

  red[tid] = p;
  __syncthreads();
  float m = -1e30f;
  for (int j = 0; j < 128; ++j) m = fmaxf(m, red[orow * 128 + j]);
  __syncthreads();
  float e = __expf(p - m);
  red[tid] = e;
  __syncthreads();
  float s = 0.f;
  for (int j = 0; j < 128; ++j) s += red[orow * 128 + j];
  out[(long)(wg * 2 + orow) * kO + oc] = e / s;
}

extern "C" void kernel_launch(void* const* d_in, const int* in_sizes, int n_in,
                              void* d_out, int out_size, void* d_ws, size_t ws_size,
                              hipStream_t stream) {
  const float* x  = (const float*)d_in[0];
  const float* Wx = (const float*)d_in[1];
  const float* Wh = (const float*)d_in[2];
  const float* b  = (const float*)d_in[3];
  const float* Wp = (const float*)d_in[4];
  const float* bp = (const float*)d_in[5];
  float* out = (float*)d_out;
  float* ws  = (float*)d_ws;

  void* args[] = { &x, &Wx, &Wh, &b, &Wp, &bp, &out, &ws };
  hipLaunchCooperativeKernel((void*)lstm_fused, dim3(256), dim3(256), args, 0, stream);
}

// Round 2
// 33009.857 us; speedup vs baseline: 1.6420x; 1.6420x over previous
//
#include <hip/hip_runtime.h>
#include <hip/hip_cooperative_groups.h>

namespace cg = cooperative_groups;

typedef _Float16 f16;
typedef _Float16 half8 __attribute__((ext_vector_type(8)));
typedef float float4v __attribute__((ext_vector_type(4)));

constexpr int kB  = 512;   // batch
constexpr int kT  = 512;   // seq len
constexpr int kI  = 128;   // input dim
constexpr int kH  = 512;   // hidden
constexpr int kNG = 2048;  // 4*H
constexpr int kO  = 128;   // output dim

constexpr int LDK = 648;   // padded K-stride (f16) for resident W in LDS; 648*2B rows
                           // bank check: byte stride 1296 -> cluster = (c + kgrp) % 8, uniform

__device__ __forceinline__ float fsig(float v)  { return 1.0f / (1.0f + __expf(-v)); }
__device__ __forceinline__ float ftanh(float v) { return 1.0f - 2.0f / (1.0f + __expf(2.0f * v)); }

// 256 WGs x 256 threads, cooperative (1 WG/CU). WG = (bg 0..7) x (ng 0..31):
// owns batch rows [bg*64, bg*64+64) and gate cols {g*512 + ng*16 + j : g in 0..3, j in 0..15}.
// Wave w (0..3) owns rows bg*64 + w*16 .. +15, all 64 cols (4 MFMA col-tiles = 4 gates).
__global__ __launch_bounds__(256, 1) void lstm_fused(
    const float* __restrict__ x,  const float* __restrict__ Wx,
    const float* __restrict__ Wh, const float* __restrict__ bias,
    const float* __restrict__ Wp, const float* __restrict__ bp,
    float* __restrict__ out, float* __restrict__ ws)
{
  cg::grid_group grid = cg::this_grid();

  // Resident weight slice, fp16, layout [col 0..63][k 0..639] with padded stride LDK.
  // col c -> global gate col (c>>4)*512 + ng*16 + (c&15); k<512 -> Wh[k][.], k>=512 -> Wx[k-512][.]
  __shared__ __align__(16) f16 w_lds[64 * LDK];   // 82,944 B

  const int tid = threadIdx.x;
  const int wg  = blockIdx.x;
  const int bg  = wg >> 5;
  const int ng  = wg & 31;
  const int b0  = bg * 64;
  const int wv  = tid >> 6;     // wave 0..3
  const int l   = tid & 63;     // lane
  const int lc  = l & 15;       // fragment row/col index
  const int lj  = l >> 4;       // k-group 0..3

  f16* h16a = (f16*)ws;             // [512][512] fp16
  f16* h16b = h16a + kB * kH;

  // ---- preprocess ----
  // zero h16a (64K threads x 8 B = 512 KB exactly)
  {
    unsigned int* p = (unsigned int*)h16a;
    int i0 = (wg * 256 + tid) * 2;
    p[i0] = 0u; p[i0 + 1] = 0u;
  }
  // stage W slice -> LDS fp16 (one time; 16-lane groups read 64B segments)
  for (int idx = tid; idx < 64 * 640; idx += 256) {
    int c = idx & 63;
    int k = idx >> 6;
    int gcol = (c >> 4) * 512 + ng * 16 + (c & 15);
    float v = (k < 512) ? Wh[(long)k * kNG + gcol]
                        : Wx[(long)(k - 512) * kNG + gcol];
    w_lds[c * LDK + k] = (f16)v;
  }
  // per-lane gate biases (col depends only on lc)
  float bb[4];
  #pragma unroll
  for (int g = 0; g < 4; ++g) bb[g] = bias[g * 512 + ng * 16 + lc];

  grid.sync();   // h16a zeroed + (superset of) block barrier for w_lds

  // c-state: lane holds rows (wv*16 + lj*4 + e), col (ng*16 + lc)
  float ce[4] = {0.f, 0.f, 0.f, 0.f};

  const int arow = b0 + wv * 16 + lc;                 // A-fragment row for this lane
  const f16* wbase = w_lds + lc * LDK + lj * 8;       // + g*16*LDK + k

  for (int t = 0; t < kT; ++t) {
    const f16* hc = (t & 1) ? h16b : h16a;
    f16*       hn = (t & 1) ? h16a : h16b;

    // issue all A-fragment loads up front (latency hidden under MFMA loop)
    half8 ah[16];
    const f16* hrowp = hc + (long)arow * kH + lj * 8;
    #pragma unroll
    for (int ks = 0; ks < 16; ++ks)
      ah[ks] = *(const half8*)(hrowp + ks * 32);

    float4v ax[8];
    const float* xrowp = x + (long)arow * (kT * kI) + (long)t * kI + lj * 8;
    #pragma unroll
    for (int ks = 0; ks < 4; ++ks) {
      ax[2 * ks]     = *(const float4v*)(xrowp + ks * 32);
      ax[2 * ks + 1] = *(const float4v*)(xrowp + ks * 32 + 4);
    }

    float4v acc[4];
    #pragma unroll
    for (int g = 0; g < 4; ++g) acc[g] = float4v{bb[g], bb[g], bb[g], bb[g]};

    // h @ Wh : K = 512 (16 k-steps of 32)
    #pragma unroll
    for (int ks = 0; ks < 16; ++ks) {
      #pragma unroll
      for (int g = 0; g < 4; ++g) {
        half8 bf = *(const half8*)(wbase + g * 16 * LDK + ks * 32);
        acc[g] = __builtin_amdgcn_mfma_f32_16x16x32_f16(ah[ks], bf, acc[g], 0, 0, 0);
      }
    }
    // x_t @ Wx : K = 128 (4 k-steps), convert f32->f16 in regs
    #pragma unroll
    for (int ks = 0; ks < 4; ++ks) {
      half8 a;
      #pragma unroll
      for (int e = 0; e < 4; ++e) {
        a[e]     = (f16)ax[2 * ks][e];
        a[e + 4] = (f16)ax[2 * ks + 1][e];
      }
      #pragma unroll
      for (int g = 0; g < 4; ++g) {
        half8 bf = *(const half8*)(wbase + g * 16 * LDK + 512 + ks * 32);
        acc[g] = __builtin_amdgcn_mfma_f32_16x16x32_f16(a, bf, acc[g], 0, 0, 0);
      }
    }

    // gate update, fully in registers. C/D: col=lc, row = lj*4 + e (within wave's 16 rows)
    #pragma unroll
    for (int e = 0; e < 4; ++e) {
      float zg = acc[0][e], zi = acc[1][e], zf = acc[2][e], zo = acc[3][e];
      float gv = ftanh(zg);
      float iv = fsig(zi);
      float fv = fsig(zf);
      float ov = fsig(zo);
      float cn = gv * iv + ce[e] * fv;
      ce[e] = cn;
      float hv = ftanh(cn) * ov;
      hn[(long)(b0 + wv * 16 + lj * 4 + e) * kH + ng * 16 + lc] = (f16)hv;
    }

    __threadfence();
    grid.sync();
  }

  // ---- projection + softmax: rows wg*2, wg*2+1 (final h is in h16a: t=511 wrote h16a)
  const f16* hf = h16a;
  float* hrow = (float*)w_lds;             // reuse LDS (recurrence done grid-wide)
  float* red  = (float*)w_lds + 2 * kH;    // after 4 KB
  for (int i = tid; i < 2 * kH; i += 256) {
    int r = i >> 9, k = i & 511;
    hrow[i] = (float)hf[(long)(wg * 2 + r) * kH + k];
  }
  __syncthreads();

  const int orow = tid >> 7;   // 0..1
  const int oc   = tid & 127;  // 0..127
  float p = bp[oc];
  #pragma unroll 8
  for (int k = 0; k < kH; ++k)
    p += hrow[orow * kH + k] * Wp[(long)k * kO + oc];

  red[tid] = p;
  __syncthreads();
  float m = -1e30f;
  for (int j = 0; j < 128; ++j) m = fmaxf(m, red[orow * 128 + j]);
  __syncthreads();
  float e = __expf(p - m);
  red[tid] = e;
  __syncthreads();
  float s = 0.f;
  for (int j = 0; j < 128; ++j) s += red[orow * 128 + j];
  out[(long)(wg * 2 + orow) * kO + oc] = e / s;
}

extern "C" void kernel_launch(void* const* d_in, const int* in_sizes, int n_in,
                              void* d_out, int out_size, void* d_ws, size_t ws_size,
                              hipStream_t stream) {
  const float* x  = (const float*)d_in[0];
  const float* Wx = (const float*)d_in[1];
  const float* Wh = (const float*)d_in[2];
  const float* b  = (const float*)d_in[3];
  const float* Wp = (const float*)d_in[4];
  const float* bp = (const float*)d_in[5];
  float* out = (float*)d_out;
  float* ws  = (float*)d_ws;

  void* args[] = { &x, &Wx, &Wh, &b, &Wp, &bp, &out, &ws };
  hipLaunchCooperativeKernel((void*)lstm_fused, dim3(256), dim3(256), args, 0, stream);
}

// Round 4
// 9585.815 us; speedup vs baseline: 5.6545x; 3.4436x over previous
//
#include <hip/hip_runtime.h>
#include <hip/hip_cooperative_groups.h>

namespace cg = cooperative_groups;

typedef _Float16 f16;
typedef _Float16 half8 __attribute__((ext_vector_type(8)));
typedef float float4v __attribute__((ext_vector_type(4)));

constexpr int kB  = 512;   // batch
constexpr int kT  = 512;   // seq len
constexpr int kI  = 128;   // input dim
constexpr int kH  = 512;   // hidden
constexpr int kNG = 2048;  // 4*H
constexpr int kO  = 128;   // output dim

constexpr int LDK = 648;   // padded K-stride (f16) for resident W in LDS

__device__ __forceinline__ float fsig(float v)  { return 1.0f / (1.0f + __expf(-v)); }
__device__ __forceinline__ float ftanh(float v) { return 1.0f - 2.0f / (1.0f + __expf(2.0f * v)); }

// 256 WGs x 256 threads (1 WG/CU, cooperative for co-residency + 2 one-time grid syncs).
// WG: bg = blockIdx&7 (batch group, 64 rows), ng = blockIdx>>3 (h-slice of 16 cols).
//   bg = &7 so the 32 WGs of one bg-group co-locate on one XCD under round-robin
//   dispatch (performance only; correctness holds for any mapping via AGENT atomics).
// Wave wv (0..3): rows bg*64 + wv*16 .. +15, all 4 gates for h-cols ng*16..+15.
// Per-step sync: 32-WG group barrier (recurrence is block-diagonal in bg),
// NOT grid.sync (measured ~60us/step in R2).
__global__ __launch_bounds__(256, 1) void lstm_fused(
    const float* __restrict__ x,  const float* __restrict__ Wx,
    const float* __restrict__ Wh, const float* __restrict__ bias,
    const float* __restrict__ Wp, const float* __restrict__ bp,
    float* __restrict__ out, float* __restrict__ ws)
{
  cg::grid_group grid = cg::this_grid();

  // Resident weight slice, fp16: [col 0..63][k 0..639], padded stride LDK.
  // col c -> global gate col (c>>4)*512 + ng*16 + (c&15); k<512 -> Wh[k], k>=512 -> Wx[k-512]
  __shared__ __align__(16) f16 w_lds[64 * LDK];   // 82,944 B

  const int tid = threadIdx.x;
  const int wg  = blockIdx.x;
  const int bg  = wg & 7;
  const int ng  = wg >> 3;
  const int b0  = bg * 64;
  const int wv  = tid >> 6;     // wave 0..3
  const int l   = tid & 63;
  const int lc  = l & 15;       // fragment row/col
  const int lj  = l >> 4;       // k-group 0..3

  f16* h16a = (f16*)ws;                 // [512][512] fp16
  f16* h16b = h16a + kB * kH;
  unsigned* bar = (unsigned*)(h16b + kB * kH);  // 8 groups x 64 uints (cnt @+0, gen @+16)

  // ---- init: zero h0 and barrier area (ws poisoned; re-init every call) ----
  {
    int gtid = wg * 256 + tid;                 // 65536 threads
    unsigned* p = (unsigned*)h16a;             // 131072 u32 = 512 KB
    p[gtid * 2] = 0u; p[gtid * 2 + 1] = 0u;
    if (gtid < 512) bar[gtid] = 0u;
  }

  // ---- one-time: stage W slice -> LDS fp16 ----
  for (int idx = tid; idx < 64 * 640; idx += 256) {
    int c = idx & 63;
    int k = idx >> 6;
    int gcol = (c >> 4) * 512 + ng * 16 + (c & 15);
    float v = (k < 512) ? Wh[(long)k * kNG + gcol]
                        : Wx[(long)(k - 512) * kNG + gcol];
    w_lds[c * LDK + k] = (f16)v;
  }
  float bb[4];
  #pragma unroll
  for (int g = 0; g < 4; ++g) bb[g] = bias[g * 512 + ng * 16 + lc];

  float ce[4] = {0.f, 0.f, 0.f, 0.f};
  const int arow = b0 + wv * 16 + lc;
  const f16* wbase = w_lds + lc * LDK + lj * 8;

  grid.sync();   // h zeroed, bar zeroed, w_lds staged, everyone resident

  unsigned* bcnt = bar + bg * 64;
  unsigned* bgen = bar + bg * 64 + 16;

  for (int t = 0; t < kT; ++t) {
    const f16* hc = (t & 1) ? h16b : h16a;
    f16*       hn = (t & 1) ? h16a : h16b;

    const f16*  hp = hc + (long)arow * kH + lj * 8;
    const float* xp = x + (long)arow * (kT * kI) + (long)t * kI + lj * 8;

    // x loads first (longest latency, consumed last)
    float4v xa[4], xb[4];
    #pragma unroll
    for (int q = 0; q < 4; ++q) {
      xa[q] = *(const float4v*)(xp + q * 32);
      xb[q] = *(const float4v*)(xp + q * 32 + 4);
    }
    half8 ah[16];
    #pragma unroll
    for (int p = 0; p < 16; ++p) ah[p] = *(const half8*)(hp + p * 32);

    float4v acc[4];
    #pragma unroll
    for (int g = 0; g < 4; ++g) acc[g] = float4v{bb[g], bb[g], bb[g], bb[g]};

    // h @ Wh : 16 k-steps of 32, B from LDS
    #pragma unroll
    for (int ks = 0; ks < 16; ++ks) {
      #pragma unroll
      for (int g = 0; g < 4; ++g) {
        half8 bf = *(const half8*)(wbase + g * 16 * LDK + ks * 32);
        acc[g] = __builtin_amdgcn_mfma_f32_16x16x32_f16(ah[ks], bf, acc[g], 0, 0, 0);
      }
    }
    // x_t @ Wx : 4 k-steps
    #pragma unroll
    for (int q = 0; q < 4; ++q) {
      half8 a;
      #pragma unroll
      for (int e = 0; e < 4; ++e) { a[e] = (f16)xa[q][e]; a[e + 4] = (f16)xb[q][e]; }
      #pragma unroll
      for (int g = 0; g < 4; ++g) {
        half8 bf = *(const half8*)(wbase + g * 16 * LDK + 512 + q * 32);
        acc[g] = __builtin_amdgcn_mfma_f32_16x16x32_f16(a, bf, acc[g], 0, 0, 0);
      }
    }

    // gate update in registers; c never leaves VGPRs
    #pragma unroll
    for (int e = 0; e < 4; ++e) {
      float gv = ftanh(acc[0][e]);
      float iv = fsig(acc[1][e]);
      float fv = fsig(acc[2][e]);
      float ov = fsig(acc[3][e]);
      float cn = gv * iv + ce[e] * fv;
      ce[e] = cn;
      hn[(long)(b0 + wv * 16 + lj * 4 + e) * kH + ng * 16 + lc] = (f16)(ftanh(cn) * ov);
    }

    // 32-WG group barrier. __syncthreads drains vmcnt (h stores in L2);
    // release-RMW at AGENT scope writes back L2 (cross-XCD safe); waiters'
    // ACQUIRE invalidates caches before next step's h reads.
    __syncthreads();
    if (tid == 0) {
      unsigned old = __hip_atomic_fetch_add(bcnt, 1u, __ATOMIC_ACQ_REL, __HIP_MEMORY_SCOPE_AGENT);
      if (old == (unsigned)(t * 32 + 31)) {
        __hip_atomic_store(bgen, (unsigned)(t + 1), __ATOMIC_RELEASE, __HIP_MEMORY_SCOPE_AGENT);
      } else {
        while (__hip_atomic_load(bgen, __ATOMIC_ACQUIRE, __HIP_MEMORY_SCOPE_AGENT) < (unsigned)(t + 1)) { }
      }
    }
    __syncthreads();
  }

  grid.sync();   // all bg-groups done before cross-group projection reads

  // ---- projection + softmax: rows wg*2, wg*2+1 (final h in h16a) ----
  const f16* hf = h16a;
  float* hrow = (float*)w_lds;             // reuse LDS
  float* red  = (float*)w_lds + 2 * kH;
  for (int i = tid; i < 2 * kH; i += 256) {
    int r = i >> 9, k = i & 511;
    hrow[i] = (float)hf[(long)(wg * 2 + r) * kH + k];
  }
  __syncthreads();

  const int orow = tid >> 7;   // 0..1
  const int oc   = tid & 127;  // 0..127
  float p = bp[oc];
  #pragma unroll 8
  for (int k = 0; k < kH; ++k)
    p += hrow[orow * kH + k] * Wp[(long)k * kO + oc];

  red[tid] = p;
  __syncthreads();
  float m = -1e30f;
  for (int j = 0; j < 128; ++j) m = fmaxf(m, red[orow * 128 + j]);
  __syncthreads();
  float e = __expf(p - m);
  red[tid] = e;
  __syncthreads();
  float s = 0.f;
  for (int j = 0; j < 128; ++j) s += red[orow * 128 + j];
  out[(long)(wg * 2 + orow) * kO + oc] = e / s;
}

extern "C" void kernel_launch(void* const* d_in, const int* in_sizes, int n_in,
                              void* d_out, int out_size, void* d_ws, size_t ws_size,
                              hipStream_t stream) {
  const float* x  = (const float*)d_in[0];
  const float* Wx = (const float*)d_in[1];
  const float* Wh = (const float*)d_in[2];
  const float* b  = (const float*)d_in[3];
  const float* Wp = (const float*)d_in[4];
  const float* bp = (const float*)d_in[5];
  float* out = (float*)d_out;
  float* ws  = (float*)d_ws;

  void* args[] = { &x, &Wx, &Wh, &b, &Wp, &bp, &out, &ws };
  hipLaunchCooperativeKernel((void*)lstm_fused, dim3(256), dim3(256), args, 0, stream);
}